// Round 2
// baseline (388.666 us; speedup 1.0000x reference)
//
#include <hip/hip_runtime.h>

#define B_SZ 2
#define E_SZ 1024
#define C_SZ 128
#define R_REL 32
#define TS 64
#define TO 64

// ---------------- Kernel A: G[b,s,o] = sum_c x[b,s,c] x[b,o,c]  -> d_ws (8 MB)
__global__ __launch_bounds__(256, 2) void compute_g(
        const float* __restrict__ x,
        float* __restrict__ G) {
    __shared__ float xs[TS][C_SZ + 4];
    __shared__ float xo[TO][C_SZ + 4];

    const int b  = blockIdx.z;
    const int s0 = blockIdx.y * TS;
    const int o0 = blockIdx.x * TO;
    const int tid = threadIdx.x;

    const float4* src_s = (const float4*)(x + (size_t)b * E_SZ * C_SZ + (size_t)s0 * C_SZ);
    const float4* src_o = (const float4*)(x + (size_t)b * E_SZ * C_SZ + (size_t)o0 * C_SZ);
    #pragma unroll
    for (int i = tid; i < TS * (C_SZ / 4); i += 256) {
        const int row = i >> 5;
        const int col = (i & 31) << 2;
        *(float4*)&xs[row][col] = src_s[i];
        *(float4*)&xo[row][col] = src_o[i];
    }
    __syncthreads();

    const int tx = tid & 15;
    const int ty = tid >> 4;
    const int si = ty << 2;
    const int oj = tx << 2;

    float acc[4][4];
    #pragma unroll
    for (int ii = 0; ii < 4; ++ii)
        #pragma unroll
        for (int jj = 0; jj < 4; ++jj) acc[ii][jj] = 0.f;

    #pragma unroll 4
    for (int c = 0; c < C_SZ; c += 4) {
        float4 a[4], bb[4];
        #pragma unroll
        for (int ii = 0; ii < 4; ++ii) a[ii]  = *(const float4*)&xs[si + ii][c];
        #pragma unroll
        for (int jj = 0; jj < 4; ++jj) bb[jj] = *(const float4*)&xo[oj + jj][c];
        #pragma unroll
        for (int ii = 0; ii < 4; ++ii)
            #pragma unroll
            for (int jj = 0; jj < 4; ++jj)
                acc[ii][jj] += a[ii].x * bb[jj].x + a[ii].y * bb[jj].y
                             + a[ii].z * bb[jj].z + a[ii].w * bb[jj].w;
    }

    // store G tile, coalesced float4
    float* gp = G + ((size_t)b * E_SZ + (size_t)(s0 + si)) * E_SZ + o0 + oj;
    #pragma unroll
    for (int ii = 0; ii < 4; ++ii) {
        float4 gv;
        gv.x = acc[ii][0]; gv.y = acc[ii][1]; gv.z = acc[ii][2]; gv.w = acc[ii][3];
        *(float4*)(gp + (size_t)ii * E_SZ) = gv;
    }
}

// ---------------- Kernel B: out[b,s,r,o] = G[b,s,o] * R[r,s,o]
// Fill-style streaming: 1 straight-line iteration/thread, both b per thread
// (R element read once). idx = (s<<13)|(r<<8)|o4 in float4 units == out idx for b=0.
__global__ __launch_bounds__(256, 8) void scale_stream(
        const float4* __restrict__ G4,
        const float4* __restrict__ R4,
        float4* __restrict__ out4) {
    const int idx = blockIdx.x * 256 + threadIdx.x;   // 0 .. 8388607
    const int o4 = idx & 255;
    const int r  = (idx >> 8) & 31;
    const int s  = idx >> 13;

    const float4 rv = R4[((size_t)r << 18) + ((size_t)s << 8) + o4];
    const float4 g0 = G4[((size_t)s << 8) + o4];
    const float4 g1 = G4[262144 + ((size_t)s << 8) + o4];

    float4 v0, v1;
    v0.x = g0.x * rv.x; v0.y = g0.y * rv.y; v0.z = g0.z * rv.z; v0.w = g0.w * rv.w;
    v1.x = g1.x * rv.x; v1.y = g1.y * rv.y; v1.z = g1.z * rv.z; v1.w = g1.w * rv.w;

    out4[idx]           = v0;
    out4[idx + 8388608] = v1;
}

extern "C" void kernel_launch(void* const* d_in, const int* in_sizes, int n_in,
                              void* d_out, int out_size, void* d_ws, size_t ws_size,
                              hipStream_t stream) {
    const float* x = (const float*)d_in[0];
    const float* R = (const float*)d_in[1];
    float* out = (float*)d_out;
    float* G = (float*)d_ws;   // needs 2*1024*1024*4 = 8 MiB

    dim3 gridA(E_SZ / TO, E_SZ / TS, B_SZ);
    compute_g<<<gridA, 256, 0, stream>>>(x, G);

    const int total4 = E_SZ * R_REL * (E_SZ / 4);     // 8388608 float4 (per b)
    scale_stream<<<total4 / 256, 256, 0, stream>>>(
        (const float4*)G, (const float4*)R, (float4*)out);
}